// Round 1
// baseline (5461.306 us; speedup 1.0000x reference)
//
#include <hip/hip_runtime.h>

// Wave-per-batch-element design: lane j owns hidden unit j (both 64-wide
// layers). Weights in VGPRs (~130), input broadcast via v_readlane (VALU
// pipe; LDS broadcast would bind the single per-CU LDS pipe). z-state is
// lane-distributed (lanes 0..39); interp/shift via __shfl. fp32 throughout.

#define DEVI __device__ __forceinline__

DEVI float rl_f(float v, int l) {
    return __int_as_float(__builtin_amdgcn_readlane(__float_as_int(v), l));
}
DEVI float rcp_f(float x) { return __builtin_amdgcn_rcpf(x); }

// robust tanh: 1 - 2/(e^{2x}+1)  (no inf/inf NaN at saturation)
DEVI float tanh_f(float x) {
    float e = __expf(2.0f * x);
    return 1.0f - 2.0f * rcp_f(e + 1.0f);
}

// dot of distributed 40-vector (lanes 0..39) with this lane's W1 column rows 8..47
DEVI float dot40(float zval, const float* w1z) {
    float a0 = 0.f, a1 = 0.f, a2 = 0.f, a3 = 0.f;
#pragma unroll
    for (int i = 0; i < 40; i += 4) {
        a0 = fmaf(w1z[i + 0], rl_f(zval, i + 0), a0);
        a1 = fmaf(w1z[i + 1], rl_f(zval, i + 1), a1);
        a2 = fmaf(w1z[i + 2], rl_f(zval, i + 2), a2);
        a3 = fmaf(w1z[i + 3], rl_f(zval, i + 3), a3);
    }
    return (a0 + a1) + (a2 + a3);
}

// One RK4 slope: k = fg(x,u) + fnn([x, z, u]).  x replicated (8 regs),
// zdot = precomputed z-part of layer-1 preactivation (per-lane).
DEVI void eval_k(const float x[8], float u0, float u1, float F, float D,
                 float zdot, const float* w1r, float b1l, const float* w2r,
                 float b2l, const float* w3r, float b3d, int lane7, float k[8])
{
    // ---- layer 1 (x & u part; z part passed in) ----
    float a = b1l + zdot;
#pragma unroll
    for (int c = 0; c < 8; ++c) a = fmaf(w1r[c], x[c], a);
    a = fmaf(w1r[48], u0, a);
    a = fmaf(w1r[49], u1, a);
    float h1 = tanh_f(a);

    // ---- layer 2: h2[lane] = tanh(b2 + sum_j h1[j]*W2[j][lane]) ----
    float c0 = b2l, c1 = 0.f, c2 = 0.f, c3 = 0.f;
#pragma unroll
    for (int j = 0; j < 64; j += 4) {
        c0 = fmaf(w2r[j + 0], rl_f(h1, j + 0), c0);
        c1 = fmaf(w2r[j + 1], rl_f(h1, j + 1), c1);
        c2 = fmaf(w2r[j + 2], rl_f(h1, j + 2), c2);
        c3 = fmaf(w2r[j + 3], rl_f(h1, j + 3), c3);
    }
    float h2 = tanh_f((c0 + c1) + (c2 + c3));

    // ---- layer 3: out[c] = sum_j h2[j]*W3[j][c]; butterfly reduce ----
    float p[8];
#pragma unroll
    for (int c = 0; c < 8; ++c) p[c] = h2 * w3r[c];
#pragma unroll
    for (int m = 1; m <= 4; m <<= 1) {
#pragma unroll
        for (int c = 0; c < 8; ++c) p[c] += __shfl_xor(p[c], m, 64);
    }
    // lane picks channel lane&7 of its group-of-8 sum, then reduce groups
    float v = p[0];
#pragma unroll
    for (int c = 1; c < 8; ++c) v = (lane7 == c) ? p[c] : v;
    v += __shfl_xor(v, 8, 64);
    v += __shfl_xor(v, 16, 64);
    v += __shfl_xor(v, 32, 64);
    v += b3d;   // v = nn_out[lane&7]

    // ---- grey-box fg (replicated across lanes), scaled coords ----
    float Hr  = fmaf(x[0], 0.3f, 0.7f);
    float CAr = fmaf(x[1], 0.2f, 0.5f);
    float CBr = fmaf(x[2], 0.2f, 0.5f);
    float Tr  = fmaf(x[3], 5.0f, 310.0f);
    float Hb  = fmaf(x[4], 0.3f, 0.7f);
    float CAb = fmaf(x[5], 0.2f, 0.5f);
    float CBb = fmaf(x[6], 0.2f, 0.5f);
    float Tb  = fmaf(x[7], 5.0f, 310.0f);

    float aA = 3.5f * CAb, aB = 1.1f * CBb;
    float rden = rcp_f(aA + aB);
    float CAd = aA * rden, CBd = aB * rden;
    float Fr = __builtin_amdgcn_sqrtf(Hr);   // kr = 1
    float Fb = __builtin_amdgcn_sqrtf(Hb);   // kb = 1
    float rTr = rcp_f(Tr);
    float k1v = 20000.0f * __expf(-3000.0f * rTr);
    float r1 = k1v * CAr;
    float rHr = rcp_f(Hr), rHb = rcp_f(Hb);  // Ar = Ab = 1

    float dHr  = F + D - Fr;
    float dCAr = (F * (1.0f - CAr) + D * (CAd - CAr)) * rHr - r1;   // CAf = 1
    float dCBr = (D * (CBd - CBr) - F * CBr) * rHr + r1;
    float dTr  = (F * (320.0f - Tr) + D * (310.0f - Tr)) * rHr
               - (40.0f / 3.0f) * rHr + (2.0f / 3.0f) * r1;  // Qr/(rho*Cp*Hr), dH1/(rho*Cp)
    float dHb  = Fr - Fb - D;
    float dCAb = (Fr * (CAr - CAb) + D * (CAb - CAd)) * rHb;
    float dCBb = (Fr * (CBr - CBb) + D * (CBb - CBd)) * rHb;
    float dTb  = Fr * (Tr - Tb) * rHb + (40.0f / 3.0f) * rHb;

    float kfg[8];
    kfg[0] = dHr  * (10.0f / 3.0f);  // / YSTD
    kfg[1] = dCAr * 5.0f;
    kfg[2] = dCBr * 5.0f;
    kfg[3] = dTr  * 0.2f;
    kfg[4] = dHb  * (10.0f / 3.0f);
    kfg[5] = dCAb * 5.0f;
    kfg[6] = dCBb * 5.0f;
    kfg[7] = dTb  * 0.2f;

#pragma unroll
    for (int c = 0; c < 8; ++c) k[c] = kfg[c] + rl_f(v, c);
}

__global__ __launch_bounds__(256, 2)
void cstr_scan_kernel(const float* __restrict__ useq, const float* __restrict__ xGz0,
                      const float* __restrict__ W1, const float* __restrict__ b1,
                      const float* __restrict__ W2, const float* __restrict__ b2,
                      const float* __restrict__ W3, const float* __restrict__ b3,
                      float* __restrict__ out)
{
    const int tid   = threadIdx.x;
    const int lane  = tid & 63;
    const int lane7 = lane & 7;
    const int b     = blockIdx.x * 4 + (tid >> 6);

    // ---- weights into VGPRs (coalesced; column `lane` of W1/W2, row of W3) ----
    float w1r[50];
#pragma unroll
    for (int i = 0; i < 50; ++i) w1r[i] = W1[i * 64 + lane];
    const float b1l = b1[lane];
    float w2r[64];
#pragma unroll
    for (int i = 0; i < 64; ++i) w2r[i] = W2[i * 64 + lane];
    const float b2l = b2[lane];
    float w3r[8];
#pragma unroll
    for (int c = 0; c < 8; ++c) w3r[c] = W3[lane * 8 + c];
    const float b3d = b3[lane7];

    // ---- state ----
    const float* xz = xGz0 + (size_t)b * 48;
    float xg[8];
#pragma unroll
    for (int c = 0; c < 8; ++c) xg[c] = xz[c];      // replicated
    float xgd = xz[lane7];                          // distributed xG[lane&7]
    float zv  = (lane < 40) ? xz[8 + lane] : 0.0f;  // [ypseq(32), upseq(8)]

    const float2* up2 = (const float2*)(useq + (size_t)b * 512);
    float* ob = out + (size_t)b * 2048;

    float ybuf = 0.0f;
    float kc[8], ks[8], xv[8];

#pragma unroll 1
    for (int t = 0; t < 256; ++t) {
        const float2 uu = up2[t];
        const float u0 = uu.x, u1 = uu.y;
        const float F = fmaf(u0, 0.1f, 1.0f);   // physical F
        const float D = fmaf(u1, 0.05f, 0.5f);  // physical D

        // ycat = [ypseq(32), xG(8)] distributed on lanes 0..39
        const float ycat = (lane < 32) ? zv : xgd;
        const float up8  = __shfl(ycat, lane + 8, 64);
        const float ziv  = (lane < 32) ? 0.5f * (ycat + up8) : zv; // interp ++ upseq
        const float zsv  = (lane < 32) ? up8 : zv;                 // shifted ++ upseq

        // z-part dot products (shared: zi used by both k2 and k3)
        const float dz1 = dot40(zv,  w1r + 8);
        const float dzi = dot40(ziv, w1r + 8);
        const float dzs = dot40(zsv, w1r + 8);

        // ---- RK4 ----
        eval_k(xg, u0, u1, F, D, dz1, w1r, b1l, w2r, b2l, w3r, b3d, lane7, kc);
#pragma unroll
        for (int c = 0; c < 8; ++c) { ks[c] = kc[c]; xv[c] = fmaf(0.005f, kc[c], xg[c]); }
        eval_k(xv, u0, u1, F, D, dzi, w1r, b1l, w2r, b2l, w3r, b3d, lane7, kc);
#pragma unroll
        for (int c = 0; c < 8; ++c) { ks[c] = fmaf(2.0f, kc[c], ks[c]); xv[c] = fmaf(0.005f, kc[c], xg[c]); }
        eval_k(xv, u0, u1, F, D, dzi, w1r, b1l, w2r, b2l, w3r, b3d, lane7, kc);
#pragma unroll
        for (int c = 0; c < 8; ++c) { ks[c] = fmaf(2.0f, kc[c], ks[c]); xv[c] = fmaf(0.01f, kc[c], xg[c]); }
        eval_k(xv, u0, u1, F, D, dzs, w1r, b1l, w2r, b2l, w3r, b3d, lane7, kc);

        // ---- output y_t = xG (pre-update); batch 8 steps -> 1 coalesced store ----
        ybuf = ((lane >> 3) == (t & 7)) ? xgd : ybuf;
        if ((t & 7) == 7) ob[(t >> 3) * 64 + lane] = ybuf;

        // ---- state update ----
#pragma unroll
        for (int c = 0; c < 8; ++c) {
            ks[c] += kc[c];
            xg[c] = fmaf(0.0016666667f, ks[c], xg[c]);  // DELTA/6
        }
        float nx = xg[0];
#pragma unroll
        for (int c = 1; c < 8; ++c) nx = (lane7 == c) ? xg[c] : nx;
        xgd = nx;

        const float zsh2  = __shfl(zv, lane + 2, 64);       // upseq shift by Nu
        const float udist = (lane & 1) ? u1 : u0;
        zv = (lane < 32) ? zsv : ((lane < 38) ? zsh2 : udist);
    }
}

extern "C" void kernel_launch(void* const* d_in, const int* in_sizes, int n_in,
                              void* d_out, int out_size, void* d_ws, size_t ws_size,
                              hipStream_t stream) {
    const float* useq = (const float*)d_in[0];
    const float* xGz0 = (const float*)d_in[1];
    const float* W1   = (const float*)d_in[2];
    const float* b1   = (const float*)d_in[3];
    const float* W2   = (const float*)d_in[4];
    const float* b2   = (const float*)d_in[5];
    const float* W3   = (const float*)d_in[6];
    const float* b3   = (const float*)d_in[7];
    float* out = (float*)d_out;

    // 8192 batch elements, one wave each; 4 waves per 256-thread block
    cstr_scan_kernel<<<dim3(2048), dim3(256), 0, stream>>>(
        useq, xGz0, W1, b1, W2, b2, W3, b3, out);
}

// Round 3
// 1233.060 us; speedup vs baseline: 4.4291x; 4.4291x over previous
//
#include <hip/hip_runtime.h>

// MFMA design: one wave per 16 batch elements, zero LDS, zero barriers.
// GEMMs oriented D[out][batch] = W^T(A-op) x act^T(B-op):
//   A-frag (weights, loop-invariant): A[m=lane&15][k=8*(lane>>4)+j]
//   B-frag (activations):             B[k=8*(lane>>4)+j][n=lane&15]
//   C/D:  D[row=4*(lane>>4)+r][col=lane&15]   (row=channel, col=batch)
// Batch index stays pinned to lane&15 through every layer, so inter-layer
// "transpose" is 16 ds_bpermute within the wave. Per-batch scalar state
// (x, z shift register, fg, RK4) lives per-lane at batch=lane&15,
// replicated across the 4 quads.

typedef _Float16 h2_t __attribute__((ext_vector_type(2)));
typedef _Float16 h8_t __attribute__((ext_vector_type(8)));
typedef __fp16  pk2_t __attribute__((ext_vector_type(2)));   // builtin's return type
typedef float f4_t __attribute__((ext_vector_type(4)));

union H8 { h8_t v; h2_t h[4]; int i[4]; };
union H2I { h2_t h; pk2_t p; int i; float _f; };

#define DEVI __device__ __forceinline__

DEVI float rcp_f(float x) { return __builtin_amdgcn_rcpf(x); }
DEVI float tanh_f(float x) {               // 1 - 2/(e^{2x}+1), NaN-free
    float e = __expf(2.0f * x);
    return 1.0f - 2.0f * rcp_f(e + 1.0f);
}
DEVI int pkrtz_i(float a, float b) { H2I u; u.p = __builtin_amdgcn_cvt_pkrtz(a, b); return u.i; }
DEVI h2_t pkrtz(float a, float b)  { H2I u; u.p = __builtin_amdgcn_cvt_pkrtz(a, b); return u.h; }
DEVI int bperm(int addr, int src) { return __builtin_amdgcn_ds_bpermute(addr, src); }
DEVI int h2i(h2_t h) { H2I u; u.h = h; return u.i; }

DEVI f4_t mfma16(h8_t a, h8_t b, f4_t c) {
    return __builtin_amdgcn_mfma_f32_16x16x32_f16(a, b, c, 0, 0, 0);
}

// 4-way select by quad index q (uniform per quad, divergent per wave)
DEVI int qsel(int q, int a, int b, int c, int d) {
    int x = (q == 0) ? a : b;
    int y = (q == 2) ? c : d;
    return (q < 2) ? x : y;
}

// grey-box CSTR+flash RHS, scaled coords, per-lane (batch = lane&15)
DEVI void fg_eval(const float x[8], float F, float D, float kfg[8]) {
    float Hr  = fmaf(x[0], 0.3f, 0.7f);
    float CAr = fmaf(x[1], 0.2f, 0.5f);
    float CBr = fmaf(x[2], 0.2f, 0.5f);
    float Tr  = fmaf(x[3], 5.0f, 310.0f);
    float Hb  = fmaf(x[4], 0.3f, 0.7f);
    float CAb = fmaf(x[5], 0.2f, 0.5f);
    float CBb = fmaf(x[6], 0.2f, 0.5f);
    float Tb  = fmaf(x[7], 5.0f, 310.0f);

    float aA = 3.5f * CAb, aB = 1.1f * CBb;
    float rden = rcp_f(aA + aB);
    float CAd = aA * rden, CBd = aB * rden;
    float Fr = __builtin_amdgcn_sqrtf(Hr);
    float Fb = __builtin_amdgcn_sqrtf(Hb);
    float rTr = rcp_f(Tr);
    float k1v = 20000.0f * __expf(-3000.0f * rTr);
    float r1 = k1v * CAr;
    float rHr = rcp_f(Hr), rHb = rcp_f(Hb);

    float dHr  = F + D - Fr;
    float dCAr = (F * (1.0f - CAr) + D * (CAd - CAr)) * rHr - r1;
    float dCBr = (D * (CBd - CBr) - F * CBr) * rHr + r1;
    float dTr  = (F * (320.0f - Tr) + D * (310.0f - Tr)) * rHr
               - (40.0f / 3.0f) * rHr + (2.0f / 3.0f) * r1;
    float dHb  = Fr - Fb - D;
    float dCAb = (Fr * (CAr - CAb) + D * (CAb - CAd)) * rHb;
    float dCBb = (Fr * (CBr - CBb) + D * (CBb - CBd)) * rHb;
    float dTb  = Fr * (Tr - Tb) * rHb + (40.0f / 3.0f) * rHb;

    kfg[0] = dHr  * (10.0f / 3.0f);
    kfg[1] = dCAr * 5.0f;
    kfg[2] = dCBr * 5.0f;
    kfg[3] = dTr  * 0.2f;
    kfg[4] = dHb  * (10.0f / 3.0f);
    kfg[5] = dCAb * 5.0f;
    kfg[6] = dCBb * 5.0f;
    kfg[7] = dTb  * 0.2f;
}

// h(C-layout, 4 tiles) -> tanh -> f16 -> B-frags for next layer (K=64)
DEVI void transition(const f4_t acc[4], int iT0, int iT1, bool qlow,
                     H8& bf0, H8& bf1) {
    int pk[4][2];
#pragma unroll
    for (int mt = 0; mt < 4; ++mt) {
        float t0 = tanh_f(acc[mt][0]);
        float t1 = tanh_f(acc[mt][1]);
        float t2 = tanh_f(acc[mt][2]);
        float t3 = tanh_f(acc[mt][3]);
        pk[mt][0] = pkrtz_i(t0, t1);
        pk[mt][1] = pkrtz_i(t2, t3);
    }
#pragma unroll
    for (int kh = 0; kh < 2; ++kh) {
        H8& bf = kh ? bf1 : bf0;
#pragma unroll
        for (int j2 = 0; j2 < 4; ++j2) {
            int idx = (j2 >> 1) ? iT1 : iT0;
            int A = bperm(idx, pk[2 * kh + 0][j2 & 1]);
            int B = bperm(idx, pk[2 * kh + 1][j2 & 1]);
            bf.i[j2] = qlow ? A : B;
        }
    }
}

struct Weights {
    h8_t w1f[4][2], w2f[4][2], w3f[2];
    f4_t b1f[4], b2f[4], b3f;
};

// one RK slope: k = fg(x,u) + fnn([x, zvariant, u])
DEVI void eval_stage(const float x[8], const h2_t yv[16], const h2_t up[4],
                     int upair_i, float F, float D, const Weights& W,
                     int q, bool qlow, int iT0, int iT1, int iN0, int iN1,
                     float k[8]) {
    // ---- build B1 frags: in = [x(8), ypart(32), upseq(8), u(2), pad] ----
    H8 f0, f1;
#pragma unroll
    for (int i = 0; i < 4; ++i) {
        int pxi = pkrtz_i(x[2 * i], x[2 * i + 1]);
        f0.i[i] = qsel(q, pxi, h2i(yv[i]), h2i(yv[4 + i]), h2i(yv[8 + i]));
        f1.i[i] = qsel(q, h2i(yv[12 + i]), h2i(up[i]),
                       (i == 0) ? upair_i : 0, 0);
    }

    // ---- layer 1 ----
    f4_t a[4];
#pragma unroll
    for (int mt = 0; mt < 4; ++mt) {
        a[mt] = mfma16(W.w1f[mt][0], f0.v, W.b1f[mt]);
        a[mt] = mfma16(W.w1f[mt][1], f1.v, a[mt]);
    }
    H8 g0, g1;
    transition(a, iT0, iT1, qlow, g0, g1);

    // ---- layer 2 ----
#pragma unroll
    for (int mt = 0; mt < 4; ++mt) {
        a[mt] = mfma16(W.w2f[mt][0], g0.v, W.b2f[mt]);
        a[mt] = mfma16(W.w2f[mt][1], g1.v, a[mt]);
    }
    transition(a, iT0, iT1, qlow, g0, g1);

    // ---- layer 3 (8 outs, rows 8..15 zero-padded) ----
    f4_t a3 = mfma16(W.w3f[0], g0.v, W.b3f);
    a3 = mfma16(W.w3f[1], g1.v, a3);

    // gather nn[c] to every lane (batch = lane&15)
    float nn[8];
#pragma unroll
    for (int c = 0; c < 8; ++c) {
        int idx = (c < 4) ? iN0 : iN1;
        nn[c] = __int_as_float(bperm(idx, __float_as_int(a3[c & 3])));
    }

    float kfg[8];
    fg_eval(x, F, D, kfg);
#pragma unroll
    for (int c = 0; c < 8; ++c) k[c] = kfg[c] + nn[c];
}

__global__ __launch_bounds__(64, 1)
void cstr_mfma_kernel(const float* __restrict__ useq, const float* __restrict__ xGz0,
                      const float* __restrict__ W1, const float* __restrict__ b1,
                      const float* __restrict__ W2, const float* __restrict__ b2,
                      const float* __restrict__ W3, const float* __restrict__ b3,
                      float* __restrict__ out)
{
    const int lane = threadIdx.x & 63;
    const int m16 = lane & 15, q = lane >> 4;
    const bool qlow = (q < 2);
    const int b0 = blockIdx.x * 16;

    // shuffle source-lane addresses (x4 for ds_bpermute)
    const int iT0 = (m16 + 16 * ((2 * q + 0) & 3)) << 2;
    const int iT1 = (m16 + 16 * ((2 * q + 1) & 3)) << 2;
    const int iN0 = m16 << 2;
    const int iN1 = (m16 + 16) << 2;

    // ---- preload weights as A-frags (f16) ----
    Weights W;
#pragma unroll
    for (int mt = 0; mt < 4; ++mt) {
#pragma unroll
        for (int kh = 0; kh < 2; ++kh) {
            H8 w1, w2;
#pragma unroll
            for (int j = 0; j < 8; ++j) {
                int k = 32 * kh + 8 * q + j;
                int n = 16 * mt + m16;
                _Float16 v1 = (k < 50) ? (_Float16)W1[k * 64 + n] : (_Float16)0.0f;
                _Float16 v2 = (_Float16)W2[k * 64 + n];
                ((_Float16*)&w1)[j] = v1;
                ((_Float16*)&w2)[j] = v2;
            }
            W.w1f[mt][kh] = w1.v;
            W.w2f[mt][kh] = w2.v;
        }
        f4_t bb1, bb2;
#pragma unroll
        for (int r = 0; r < 4; ++r) {
            bb1[r] = b1[16 * mt + 4 * q + r];
            bb2[r] = b2[16 * mt + 4 * q + r];
        }
        W.b1f[mt] = bb1;
        W.b2f[mt] = bb2;
    }
#pragma unroll
    for (int kh = 0; kh < 2; ++kh) {
        H8 w3;
#pragma unroll
        for (int j = 0; j < 8; ++j) {
            int k = 32 * kh + 8 * q + j;
            ((_Float16*)&w3)[j] = (m16 < 8) ? (_Float16)W3[k * 8 + m16] : (_Float16)0.0f;
        }
        W.w3f[kh] = w3.v;
    }
    {
        f4_t bb3;
#pragma unroll
        for (int r = 0; r < 4; ++r) {
            int c = 4 * q + r;
            bb3[r] = (c < 8) ? b3[c] : 0.0f;
        }
        W.b3f = bb3;
    }

    // ---- per-batch state (batch = lane&15, quad-replicated) ----
    const float* xz = xGz0 + (size_t)(b0 + m16) * 48;
    float xg[8];
#pragma unroll
    for (int c = 0; c < 8; ++c) xg[c] = xz[c];
    h2_t p[16];                       // ypseq (32) as f16 pairs
#pragma unroll
    for (int i = 0; i < 16; ++i) p[i] = pkrtz(xz[8 + 2 * i], xz[9 + 2 * i]);
    h2_t up[4];                       // upseq (8) as f16 pairs
#pragma unroll
    for (int i = 0; i < 4; ++i) up[i] = pkrtz(xz[40 + 2 * i], xz[41 + 2 * i]);

    const float* ub = useq + (size_t)(b0 + m16) * 512;
    float* ob = out + (size_t)(b0 + m16) * 2048;

    float kc[8], ks[8], xv[8];

#pragma unroll 1
    for (int t = 0; t < 256; ++t) {
        const float2 uu = *(const float2*)(ub + 2 * t);
        const float u0 = uu.x, u1 = uu.y;
        const float F = fmaf(u0, 0.1f, 1.0f);
        const float D = fmaf(u1, 0.05f, 0.5f);
        const int upair_i = pkrtz_i(u0, u1);

        // ycat pairs = [ypseq(16 pairs), xG(4 pairs)]
        h2_t pc[20];
#pragma unroll
        for (int i = 0; i < 16; ++i) pc[i] = p[i];
#pragma unroll
        for (int i = 0; i < 4; ++i) pc[16 + i] = pkrtz(xg[2 * i], xg[2 * i + 1]);
        // interp & shifted variants (f16 packed math)
        h2_t pi[16], ps[16];
        const h2_t half2c = { (_Float16)0.5f, (_Float16)0.5f };
#pragma unroll
        for (int i = 0; i < 16; ++i) {
            pi[i] = (pc[i] + pc[i + 4]) * half2c;
            ps[i] = pc[i + 4];
        }

        // ---- RK4 ----
        eval_stage(xg, p,  up, upair_i, F, D, W, q, qlow, iT0, iT1, iN0, iN1, kc);
#pragma unroll
        for (int c = 0; c < 8; ++c) { ks[c] = kc[c]; xv[c] = fmaf(0.005f, kc[c], xg[c]); }
        eval_stage(xv, pi, up, upair_i, F, D, W, q, qlow, iT0, iT1, iN0, iN1, kc);
#pragma unroll
        for (int c = 0; c < 8; ++c) { ks[c] = fmaf(2.0f, kc[c], ks[c]); xv[c] = fmaf(0.005f, kc[c], xg[c]); }
        eval_stage(xv, pi, up, upair_i, F, D, W, q, qlow, iT0, iT1, iN0, iN1, kc);
#pragma unroll
        for (int c = 0; c < 8; ++c) { ks[c] = fmaf(2.0f, kc[c], ks[c]); xv[c] = fmaf(0.01f, kc[c], xg[c]); }
        eval_stage(xv, ps, up, upair_i, F, D, W, q, qlow, iT0, iT1, iN0, iN1, kc);

        // ---- store y_t = xG (pre-update): quad q stores channels 2q,2q+1 ----
        {
            float s0 = (q == 0) ? xg[0] : (q == 1) ? xg[2] : (q == 2) ? xg[4] : xg[6];
            float s1 = (q == 0) ? xg[1] : (q == 1) ? xg[3] : (q == 2) ? xg[5] : xg[7];
            float2 st = { s0, s1 };
            *(float2*)(ob + t * 8 + 2 * q) = st;
        }

        // ---- state update ----
#pragma unroll
        for (int c = 0; c < 8; ++c) {
            ks[c] += kc[c];
            xg[c] = fmaf(0.0016666667f, ks[c], xg[c]);   // DELTA/6
        }
#pragma unroll
        for (int i = 0; i < 16; ++i) p[i] = ps[i];       // ypseq <- shifted (incl old xG)
        up[0] = up[1]; up[1] = up[2]; up[2] = up[3];
        { H2I u; u.i = upair_i; up[3] = u.h; }           // upseq <- [old[2:], u]
    }
}

extern "C" void kernel_launch(void* const* d_in, const int* in_sizes, int n_in,
                              void* d_out, int out_size, void* d_ws, size_t ws_size,
                              hipStream_t stream) {
    const float* useq = (const float*)d_in[0];
    const float* xGz0 = (const float*)d_in[1];
    const float* W1   = (const float*)d_in[2];
    const float* b1   = (const float*)d_in[3];
    const float* W2   = (const float*)d_in[4];
    const float* b2   = (const float*)d_in[5];
    const float* W3   = (const float*)d_in[6];
    const float* b3   = (const float*)d_in[7];
    float* out = (float*)d_out;

    // 8192 batch / 16 per wave = 512 waves
    cstr_mfma_kernel<<<dim3(512), dim3(64), 0, stream>>>(
        useq, xGz0, W1, b1, W2, b2, W3, b3, out);
}

// Round 4
// 1200.192 us; speedup vs baseline: 4.5504x; 1.0274x over previous
//
#include <hip/hip_runtime.h>

// R4: 2-wave channel-split MFMA design. Block = 128 thr = 2 waves per group
// of 16 batch elements; wave w owns output channels [32w,32w+32) of layers
// 1&2 (2 M-tiles each). Inter-layer activation exchange via LDS (stride-36
// rows -> 2-way bank aliasing only). sigma-folding: tanh(a)=1-2*sigma(2a),
// with -2 and 2*log2(e) folded into weights/biases so each activation is
// rcp(1+exp2(c)). Per-batch state (x, z shift reg, fg, RK4) replicated in
// both waves (deterministic identical compute); wave 0 stores output.

typedef _Float16 h2_t __attribute__((ext_vector_type(2)));
typedef _Float16 h8_t __attribute__((ext_vector_type(8)));
typedef __fp16  pk2_t __attribute__((ext_vector_type(2)));
typedef float f4_t __attribute__((ext_vector_type(4)));

union H8 { h8_t v; h2_t h[4]; int i[4]; int4 i4; };
union H2I { h2_t h; pk2_t p; int i; float _f; };

#define DEVI __device__ __forceinline__

DEVI float rcp_f(float x) { return __builtin_amdgcn_rcpf(x); }
#if __has_builtin(__builtin_amdgcn_exp2f)
DEVI float exp2_f(float x) { return __builtin_amdgcn_exp2f(x); }
#else
DEVI float exp2_f(float x) { return __expf(x * 0.69314718056f); }
#endif
DEVI int pkrtz_i(float a, float b) { H2I u; u.p = __builtin_amdgcn_cvt_pkrtz(a, b); return u.i; }
DEVI h2_t pkrtz(float a, float b)  { H2I u; u.p = __builtin_amdgcn_cvt_pkrtz(a, b); return u.h; }
DEVI int bperm(int addr, int src) { return __builtin_amdgcn_ds_bpermute(addr, src); }
DEVI int h2i(h2_t h) { H2I u; u.h = h; return u.i; }

DEVI f4_t mfma16(h8_t a, h8_t b, f4_t c) {
    return __builtin_amdgcn_mfma_f32_16x16x32_f16(a, b, c, 0, 0, 0);
}

DEVI int qsel(int q, int a, int b, int c, int d) {
    int x = (q == 0) ? a : b;
    int y = (q == 2) ? c : d;
    return (q < 2) ? x : y;
}

// grey-box CSTR+flash RHS, scaled coords, per-lane (batch = lane&15)
DEVI void fg_eval(const float x[8], float F, float D, float kfg[8]) {
    float Hr  = fmaf(x[0], 0.3f, 0.7f);
    float CAr = fmaf(x[1], 0.2f, 0.5f);
    float CBr = fmaf(x[2], 0.2f, 0.5f);
    float Tr  = fmaf(x[3], 5.0f, 310.0f);
    float Hb  = fmaf(x[4], 0.3f, 0.7f);
    float CAb = fmaf(x[5], 0.2f, 0.5f);
    float CBb = fmaf(x[6], 0.2f, 0.5f);
    float Tb  = fmaf(x[7], 5.0f, 310.0f);

    float aA = 3.5f * CAb, aB = 1.1f * CBb;
    float rden = rcp_f(aA + aB);
    float CAd = aA * rden, CBd = aB * rden;
    float Fr = __builtin_amdgcn_sqrtf(Hr);
    float Fb = __builtin_amdgcn_sqrtf(Hb);
    float rTr = rcp_f(Tr);
    float k1v = 20000.0f * __expf(-3000.0f * rTr);
    float r1 = k1v * CAr;
    float rHr = rcp_f(Hr), rHb = rcp_f(Hb);

    float dHr  = F + D - Fr;
    float dCAr = (F * (1.0f - CAr) + D * (CAd - CAr)) * rHr - r1;
    float dCBr = (D * (CBd - CBr) - F * CBr) * rHr + r1;
    float dTr  = (F * (320.0f - Tr) + D * (310.0f - Tr)) * rHr
               - (40.0f / 3.0f) * rHr + (2.0f / 3.0f) * r1;
    float dHb  = Fr - Fb - D;
    float dCAb = (Fr * (CAr - CAb) + D * (CAb - CAd)) * rHb;
    float dCBb = (Fr * (CBr - CBb) + D * (CBb - CBd)) * rHb;
    float dTb  = Fr * (Tr - Tb) * rHb + (40.0f / 3.0f) * rHb;

    kfg[0] = dHr  * (10.0f / 3.0f);
    kfg[1] = dCAr * 5.0f;
    kfg[2] = dCBr * 5.0f;
    kfg[3] = dTr  * 0.2f;
    kfg[4] = dHb  * (10.0f / 3.0f);
    kfg[5] = dCAb * 5.0f;
    kfg[6] = dCBb * 5.0f;
    kfg[7] = dTb  * 0.2f;
}

struct Weights {
    h8_t a1[2][2], a2[2][2], a3[2];
    f4_t b1f[2], b2f[2], b3f;
};

// sigma transition through LDS: this wave's 2 C-tiles -> sigma(f16 pairs)
// -> LDS row[batch] -> both waves read full-K B-frags.
DEVI void transition_lds(const f4_t acc[2], int* __restrict__ buf,
                         int wrbase, int rdbase, H8& g0, H8& g1) {
#pragma unroll
    for (int ct = 0; ct < 2; ++ct) {
        float s0 = rcp_f(1.0f + exp2_f(acc[ct][0]));
        float s1 = rcp_f(1.0f + exp2_f(acc[ct][1]));
        float s2 = rcp_f(1.0f + exp2_f(acc[ct][2]));
        float s3 = rcp_f(1.0f + exp2_f(acc[ct][3]));
        int2 pk = { pkrtz_i(s0, s1), pkrtz_i(s2, s3) };
        *(int2*)(buf + wrbase + 8 * ct) = pk;          // ds_write_b64
    }
    __syncthreads();
    g0.i4 = *(const int4*)(buf + rdbase);               // ds_read_b128
    g1.i4 = *(const int4*)(buf + rdbase + 16);
}

// one RK slope: k = fg(x,u) + fnn([x, zvariant, u])
DEVI void eval_stage(const float x[8], const h2_t yv[16], const h2_t up[4],
                     int upair_i, float F, float D, const Weights& W,
                     int q, int wrbase, int rdbase,
                     int* __restrict__ buf0, int* __restrict__ buf1,
                     int iN0, int iN1, float k[8]) {
    // ---- build B1 frags: in = [x(8), ypart(32), upseq(8), u(2), pad] ----
    H8 f0, f1;
#pragma unroll
    for (int i = 0; i < 4; ++i) {
        int pxi = pkrtz_i(x[2 * i], x[2 * i + 1]);
        f0.i[i] = qsel(q, pxi, h2i(yv[i]), h2i(yv[4 + i]), h2i(yv[8 + i]));
        f1.i[i] = qsel(q, h2i(yv[12 + i]), h2i(up[i]),
                       (i == 0) ? upair_i : 0, 0);
    }

    // ---- layer 1 (this wave's 2 M-tiles) ----
    f4_t a[2];
#pragma unroll
    for (int ct = 0; ct < 2; ++ct) {
        a[ct] = mfma16(W.a1[ct][0], f0.v, W.b1f[ct]);
        a[ct] = mfma16(W.a1[ct][1], f1.v, a[ct]);
    }
    H8 g0, g1;
    transition_lds(a, buf0, wrbase, rdbase, g0, g1);

    // ---- layer 2 ----
#pragma unroll
    for (int ct = 0; ct < 2; ++ct) {
        a[ct] = mfma16(W.a2[ct][0], g0.v, W.b2f[ct]);
        a[ct] = mfma16(W.a2[ct][1], g1.v, a[ct]);
    }
    transition_lds(a, buf1, wrbase, rdbase, g0, g1);

    // ---- layer 3 (full K, replicated in both waves) ----
    f4_t a3 = mfma16(W.a3[0], g0.v, W.b3f);
    a3 = mfma16(W.a3[1], g1.v, a3);

    // gather nn[c] to every lane (batch = lane&15)
    float nn[8];
#pragma unroll
    for (int c = 0; c < 8; ++c) {
        int idx = (c < 4) ? iN0 : iN1;
        nn[c] = __int_as_float(bperm(idx, __float_as_int(a3[c & 3])));
    }

    float kfg[8];
    fg_eval(x, F, D, kfg);
#pragma unroll
    for (int c = 0; c < 8; ++c) k[c] = kfg[c] + nn[c];
}

__global__ __launch_bounds__(128, 1)
void cstr_mfma2_kernel(const float* __restrict__ useq, const float* __restrict__ xGz0,
                       const float* __restrict__ W1, const float* __restrict__ b1,
                       const float* __restrict__ W2, const float* __restrict__ b2,
                       const float* __restrict__ W3, const float* __restrict__ b3,
                       float* __restrict__ out)
{
    const int tid = threadIdx.x;
    const int w = tid >> 6;                 // wave in block (channel half)
    const int lane = tid & 63;
    const int m16 = lane & 15, q = lane >> 4;
    const int b0 = blockIdx.x * 16;

    __shared__ int lds[4][16 * 36];         // 4 rotating sigma buffers, 9216 B

    const int wrbase = m16 * 36 + 16 * w + 2 * q;
    const int rdbase = m16 * 36 + 4 * q;
    const int iN0 = m16 << 2;
    const int iN1 = (m16 + 16) << 2;

    const float S1 = 2.0f * 1.4426950408889634f;   // 2*log2(e)

    // ---- preload weights (sigma-folded) ----
    Weights W;
#pragma unroll
    for (int ct = 0; ct < 2; ++ct) {
        const int mt = 2 * w + ct;
#pragma unroll
        for (int kh = 0; kh < 2; ++kh) {
            H8 w1f, w2f;
#pragma unroll
            for (int j = 0; j < 8; ++j) {
                int k = 32 * kh + 8 * q + j;
                int n = 16 * mt + m16;
                float v1 = (k < 50) ? S1 * W1[k * 64 + n] : 0.0f;
                float v2 = -2.0f * S1 * W2[k * 64 + n];
                ((_Float16*)&w1f)[j] = (_Float16)v1;
                ((_Float16*)&w2f)[j] = (_Float16)v2;
            }
            W.a1[ct][kh] = w1f.v;
            W.a2[ct][kh] = w2f.v;
        }
        f4_t bb1, bb2;
#pragma unroll
        for (int r = 0; r < 4; ++r) {
            int ch = 16 * mt + 4 * q + r;
            bb1[r] = S1 * b1[ch];
            float cs = 0.0f;
            for (int j = 0; j < 64; ++j) cs += W2[j * 64 + ch];
            bb2[r] = S1 * (b2[ch] + cs);
        }
        W.b1f[ct] = bb1;
        W.b2f[ct] = bb2;
    }
#pragma unroll
    for (int kh = 0; kh < 2; ++kh) {
        H8 w3f;
#pragma unroll
        for (int j = 0; j < 8; ++j) {
            int k = 32 * kh + 8 * q + j;
            ((_Float16*)&w3f)[j] = (m16 < 8) ? (_Float16)(-2.0f * W3[k * 8 + m16])
                                             : (_Float16)0.0f;
        }
        W.a3[kh] = w3f.v;
    }
    {
        f4_t bb3;
#pragma unroll
        for (int r = 0; r < 4; ++r) {
            int c = 4 * q + r;
            float v = 0.0f;
            if (c < 8) {
                float cs = 0.0f;
                for (int j = 0; j < 64; ++j) cs += W3[j * 8 + c];
                v = b3[c] + cs;
            }
            bb3[r] = v;
        }
        W.b3f = bb3;
    }

    // ---- per-batch state (batch = lane&15; replicated across quads+waves) ----
    const float* xz = xGz0 + (size_t)(b0 + m16) * 48;
    float xg[8];
#pragma unroll
    for (int c = 0; c < 8; ++c) xg[c] = xz[c];
    h2_t p[16];
#pragma unroll
    for (int i = 0; i < 16; ++i) p[i] = pkrtz(xz[8 + 2 * i], xz[9 + 2 * i]);
    h2_t up[4];
#pragma unroll
    for (int i = 0; i < 4; ++i) up[i] = pkrtz(xz[40 + 2 * i], xz[41 + 2 * i]);

    const float* ub = useq + (size_t)(b0 + m16) * 512;
    float* ob = out + (size_t)(b0 + m16) * 2048;

    float kc[8], ks[8], xv[8];

#pragma unroll 1
    for (int t = 0; t < 256; ++t) {
        const float2 uu = *(const float2*)(ub + 2 * t);
        const float u0 = uu.x, u1 = uu.y;
        const float F = fmaf(u0, 0.1f, 1.0f);
        const float D = fmaf(u1, 0.05f, 0.5f);
        const int upair_i = pkrtz_i(u0, u1);

        // ycat pairs = [ypseq(16 pairs), xG(4 pairs)]
        h2_t pc[20];
#pragma unroll
        for (int i = 0; i < 16; ++i) pc[i] = p[i];
#pragma unroll
        for (int i = 0; i < 4; ++i) pc[16 + i] = pkrtz(xg[2 * i], xg[2 * i + 1]);
        h2_t pi[16], ps[16];
        const h2_t half2c = { (_Float16)0.5f, (_Float16)0.5f };
#pragma unroll
        for (int i = 0; i < 16; ++i) {
            pi[i] = (pc[i] + pc[i + 4]) * half2c;
            ps[i] = pc[i + 4];
        }

        // ---- RK4 (LDS buffers rotate per transition; >=3-barrier WAR margin) ----
        eval_stage(xg, p,  up, upair_i, F, D, W, q, wrbase, rdbase,
                   lds[0], lds[1], iN0, iN1, kc);
#pragma unroll
        for (int c = 0; c < 8; ++c) { ks[c] = kc[c]; xv[c] = fmaf(0.005f, kc[c], xg[c]); }
        eval_stage(xv, pi, up, upair_i, F, D, W, q, wrbase, rdbase,
                   lds[2], lds[3], iN0, iN1, kc);
#pragma unroll
        for (int c = 0; c < 8; ++c) { ks[c] = fmaf(2.0f, kc[c], ks[c]); xv[c] = fmaf(0.005f, kc[c], xg[c]); }
        eval_stage(xv, pi, up, upair_i, F, D, W, q, wrbase, rdbase,
                   lds[0], lds[1], iN0, iN1, kc);
#pragma unroll
        for (int c = 0; c < 8; ++c) { ks[c] = fmaf(2.0f, kc[c], ks[c]); xv[c] = fmaf(0.01f, kc[c], xg[c]); }
        eval_stage(xv, ps, up, upair_i, F, D, W, q, wrbase, rdbase,
                   lds[2], lds[3], iN0, iN1, kc);

        // ---- store y_t = xG (pre-update); wave 0 only ----
        if (w == 0) {
            float s0 = (q == 0) ? xg[0] : (q == 1) ? xg[2] : (q == 2) ? xg[4] : xg[6];
            float s1 = (q == 0) ? xg[1] : (q == 1) ? xg[3] : (q == 2) ? xg[5] : xg[7];
            float2 st = { s0, s1 };
            *(float2*)(ob + t * 8 + 2 * q) = st;
        }

        // ---- state update ----
#pragma unroll
        for (int c = 0; c < 8; ++c) {
            ks[c] += kc[c];
            xg[c] = fmaf(0.0016666667f, ks[c], xg[c]);   // DELTA/6
        }
#pragma unroll
        for (int i = 0; i < 16; ++i) p[i] = ps[i];
        up[0] = up[1]; up[1] = up[2]; up[2] = up[3];
        { H2I u; u.i = upair_i; up[3] = u.h; }
    }
}

extern "C" void kernel_launch(void* const* d_in, const int* in_sizes, int n_in,
                              void* d_out, int out_size, void* d_ws, size_t ws_size,
                              hipStream_t stream) {
    const float* useq = (const float*)d_in[0];
    const float* xGz0 = (const float*)d_in[1];
    const float* W1   = (const float*)d_in[2];
    const float* b1   = (const float*)d_in[3];
    const float* W2   = (const float*)d_in[4];
    const float* b2   = (const float*)d_in[5];
    const float* W3   = (const float*)d_in[6];
    const float* b3   = (const float*)d_in[7];
    float* out = (float*)d_out;

    // 8192 batch / 16 per group = 512 blocks of 2 waves (channel halves)
    cstr_mfma2_kernel<<<dim3(512), dim3(128), 0, stream>>>(
        useq, xGz0, W1, b1, W2, b2, W3, b3, out);
}